// Round 2
// baseline (423.121 us; speedup 1.0000x reference)
//
#include <hip/hip_runtime.h>
#include <hip/hip_bf16.h>
#include <stdint.h>

// Problem constants (S=1024, B=2 -> T=2048 tokens)
#define TT 2048
#define DD 512
#define FF 2048
#define EE 8

typedef unsigned short u16;
typedef __attribute__((ext_vector_type(8))) unsigned short ushort8v;
typedef __attribute__((ext_vector_type(8))) short short8;     // bf16x8 frag (4 VGPRs)
typedef __attribute__((ext_vector_type(4))) float float4v;

__device__ __forceinline__ float bf2f(u16 b) {
    return __uint_as_float(((unsigned)b) << 16);
}
__device__ __forceinline__ u16 f2bf(float f) {
    unsigned u = __float_as_uint(f);
    u += 0x7FFF + ((u >> 16) & 1);   // round-to-nearest-even
    return (u16)(u >> 16);
}

// ---------------- workspace layout (bytes) ----------------
// hbuf bf16 [6144][2048] : rows 0..4095 routed (bucket order), 4096+t shared
// xg   bf16 [6144][512]  : rows 0..4095 gathered x (bucket order), 4096+t = x[t]
#define WS_HB   0ull
#define WS_XG   (WS_HB + 6144ull*2048*2)           // 25,165,824
#define WS_CNT  (WS_XG + 6144ull*512*2)            // 31,457,280
#define WS_OFFS (WS_CNT + 32)
#define WS_FILL (WS_OFFS + 32)
#define WS_ME   (WS_FILL + 32)                      // int  [2048][2] expert ids
#define WS_MW   (WS_ME + 4096*4)                    // float[2048][2] weights
#define WS_RT   (WS_MW + 4096*4)                    // int  rtok[4096] row -> token
#define WS_WROW (WS_RT + 4096*4)                    // float wrow[4096] row -> weight
// total ~31.5 MB

// ---------------- kernel 1: gate (fp32 math, matches np ref) ----------------
__global__ void gate_k(const float* __restrict__ x, const float* __restrict__ Wg,
                       const float* __restrict__ bg,
                       int* __restrict__ cnt, int* __restrict__ metaE,
                       float* __restrict__ metaW) {
    int t = blockIdx.x;
    int lane = threadIdx.x;   // 64
    const float* xp = x + (size_t)t * DD + lane * 8;
    float4v x0 = *(const float4v*)xp;
    float4v x1 = *(const float4v*)(xp + 4);
    float xf[8] = {x0[0], x0[1], x0[2], x0[3], x1[0], x1[1], x1[2], x1[3]};
    float acc[EE] = {0.f, 0.f, 0.f, 0.f, 0.f, 0.f, 0.f, 0.f};
#pragma unroll
    for (int g = 0; g < 8; ++g) {
        int d = lane * 8 + g;
        const float* wp = Wg + (size_t)d * EE;
        float4v w0 = *(const float4v*)wp;
        float4v w1 = *(const float4v*)(wp + 4);
        acc[0] += xf[g] * w0[0]; acc[1] += xf[g] * w0[1];
        acc[2] += xf[g] * w0[2]; acc[3] += xf[g] * w0[3];
        acc[4] += xf[g] * w1[0]; acc[5] += xf[g] * w1[1];
        acc[6] += xf[g] * w1[2]; acc[7] += xf[g] * w1[3];
    }
#pragma unroll
    for (int off = 1; off < 64; off <<= 1) {
#pragma unroll
        for (int e = 0; e < EE; ++e) acc[e] += __shfl_xor(acc[e], off, 64);
    }
    if (lane == 0) {
#pragma unroll
        for (int e = 0; e < EE; ++e) acc[e] += bg[e];
        int e0 = 0; float l0 = acc[0];
#pragma unroll
        for (int e = 1; e < EE; ++e) if (acc[e] > l0) { l0 = acc[e]; e0 = e; }
        int e1 = -1; float l1 = -3.4e38f;
#pragma unroll
        for (int e = 0; e < EE; ++e)
            if (e != e0 && acc[e] > l1) { l1 = acc[e]; e1 = e; }
        float ex = __expf(l1 - l0);      // l1 <= l0, stable
        float w0 = 1.f / (1.f + ex);
        float w1 = 1.f - w0;
        atomicAdd(&cnt[e0], 1);
        atomicAdd(&cnt[e1], 1);
        metaE[2 * t] = e0; metaE[2 * t + 1] = e1;
        metaW[2 * t] = w0; metaW[2 * t + 1] = w1;
    }
}

// ---------------- kernel 2: scan ----------------
__global__ void scan_k(const int* __restrict__ cnt, int* __restrict__ offs) {
    if (threadIdx.x == 0 && blockIdx.x == 0) {
        int s = 0;
        for (int e = 0; e < EE; ++e) { offs[e] = s; s += cnt[e]; }
    }
}

// ---------------- kernel 3: fill (assign rows + gather x -> bf16) ----------------
__global__ void fill_k(const float* __restrict__ x, const int* __restrict__ offs,
                       int* __restrict__ fill, const int* __restrict__ metaE,
                       const float* __restrict__ metaW, int* __restrict__ rtok,
                       float* __restrict__ wrow, u16* __restrict__ xg) {
    int t = blockIdx.x;
    int lane = threadIdx.x;
    int r0 = 0, r1 = 0;
    if (lane == 0) {
        int e0 = metaE[2 * t], e1 = metaE[2 * t + 1];
        r0 = offs[e0] + atomicAdd(&fill[e0], 1);
        r1 = offs[e1] + atomicAdd(&fill[e1], 1);
        rtok[r0] = t; rtok[r1] = t;
        wrow[r0] = metaW[2 * t];
        wrow[r1] = metaW[2 * t + 1];
    }
    r0 = __shfl(r0, 0, 64);
    r1 = __shfl(r1, 0, 64);
    const float* xp = x + (size_t)t * DD + lane * 8;
    float4v v0 = *(const float4v*)xp;
    float4v v1 = *(const float4v*)(xp + 4);
    ushort8v xv;
#pragma unroll
    for (int j = 0; j < 4; ++j) xv[j] = f2bf(v0[j]);
#pragma unroll
    for (int j = 0; j < 4; ++j) xv[4 + j] = f2bf(v1[j]);
    *(ushort8v*)(xg + (size_t)r0 * DD + lane * 8) = xv;
    *(ushort8v*)(xg + (size_t)r1 * DD + lane * 8) = xv;
    *(ushort8v*)(xg + (size_t)(4096 + t) * DD + lane * 8) = xv;  // shared-expert copy
}

// ---------------- kernel 4: GEMM A  h = relu(A @ W1 + b1) ----------------
// grid: routed 8*16*16=2048 blocks, shared 16*16=256 -> 2304. 256 threads.
__global__ __launch_bounds__(256) void gemmA_k(
    const u16* __restrict__ xg,
    const float* __restrict__ W1, const float* __restrict__ b1,
    const float* __restrict__ Ws1, const float* __restrict__ bs1,
    const int* __restrict__ cnt, const int* __restrict__ offs,
    u16* __restrict__ hbuf) {
    int vb = blockIdx.x;
    int tid = threadIdx.x;
    int rt, ct, Mloc;
    const u16* Asrc;
    const float *Bsrc, *bias;
    int hRowBase;
    if (vb < 2048) {
        int e = vb >> 8;
        rt = (vb >> 4) & 15; ct = vb & 15;
        int M = cnt[e];
        if (rt * 128 >= M) return;
        Mloc = M - rt * 128;
        int rb = offs[e] + rt * 128;
        Asrc = xg + (size_t)rb * DD;
        Bsrc = W1 + (size_t)e * DD * FF;
        bias = b1 + e * FF;
        hRowBase = rb;
    } else {
        int v = vb - 2048;
        rt = v >> 4; ct = v & 15;
        Mloc = 128;
        Asrc = xg + (size_t)(4096 + rt * 128) * DD;
        Bsrc = Ws1;
        bias = bs1;
        hRowBase = 4096 + rt * 128;
    }
    int n0 = ct * 128;
    int lane = tid & 63, w = tid >> 6, ln = lane & 15, quad = lane >> 4;

    __shared__ __align__(16) u16 As[128 * 32];
    __shared__ __align__(16) u16 Bst[128 * 32];   // B transposed: [n][k], k-pairs packed

    float4v acc[4][4];
#pragma unroll
    for (int a = 0; a < 4; ++a)
#pragma unroll
        for (int b = 0; b < 4; ++b) acc[a][b] = (float4v){0.f, 0.f, 0.f, 0.f};

    for (int kt = 0; kt < DD / 32; ++kt) {
        int k0 = kt * 32;
        // stage A [128][32] (bf16 source)
#pragma unroll
        for (int r = 0; r < 2; ++r) {
            int lr = (tid >> 2) + r * 64;
            int kg = tid & 3;
            ushort8v v = (ushort8v){0,0,0,0,0,0,0,0};
            if (lr < Mloc) v = *(const ushort8v*)(Asrc + (size_t)lr * DD + k0 + kg * 8);
            *(ushort8v*)&As[lr * 32 + kg * 8] = v;
        }
        // stage B transposed from fp32 source, cast to bf16, pack k-pairs
        {
            int k2 = tid & 15;      // k pair index
            int ng = tid >> 4;      // n group of 8
            const float* bp = Bsrc + (size_t)(k0 + 2 * k2) * FF + n0 + ng * 8;
            float4v a0 = *(const float4v*)bp;
            float4v a1 = *(const float4v*)(bp + 4);
            float4v c0 = *(const float4v*)(bp + FF);
            float4v c1 = *(const float4v*)(bp + FF + 4);
#pragma unroll
            for (int j = 0; j < 4; ++j) {
                unsigned u = (unsigned)f2bf(a0[j]) | ((unsigned)f2bf(c0[j]) << 16);
                *(unsigned*)&Bst[(ng * 8 + j) * 32 + 2 * k2] = u;
            }
#pragma unroll
            for (int j = 0; j < 4; ++j) {
                unsigned u = (unsigned)f2bf(a1[j]) | ((unsigned)f2bf(c1[j]) << 16);
                *(unsigned*)&Bst[(ng * 8 + 4 + j) * 32 + 2 * k2] = u;
            }
        }
        __syncthreads();
        short8 Af[4], Bf[4];
#pragma unroll
        for (int a = 0; a < 4; ++a)
            Af[a] = *(const short8*)&As[((w & 1) * 64 + a * 16 + ln) * 32 + quad * 8];
#pragma unroll
        for (int b = 0; b < 4; ++b)
            Bf[b] = *(const short8*)&Bst[((w >> 1) * 64 + b * 16 + ln) * 32 + quad * 8];
#pragma unroll
        for (int a = 0; a < 4; ++a)
#pragma unroll
            for (int b = 0; b < 4; ++b)
                acc[a][b] = __builtin_amdgcn_mfma_f32_16x16x32_bf16(Af[a], Bf[b], acc[a][b], 0, 0, 0);
        __syncthreads();
    }
    // epilogue: +b1, relu, store bf16
#pragma unroll
    for (int b = 0; b < 4; ++b) {
        int n = n0 + (w >> 1) * 64 + b * 16 + ln;
        float bv = bias[n];
#pragma unroll
        for (int a = 0; a < 4; ++a) {
#pragma unroll
            for (int i = 0; i < 4; ++i) {
                int lr = (w & 1) * 64 + a * 16 + quad * 4 + i;
                if (lr < Mloc) {
                    float v = acc[a][b][i] + bv;
                    v = v > 0.f ? v : 0.f;
                    hbuf[(size_t)(hRowBase + lr) * FF + n] = f2bf(v);
                }
            }
        }
    }
}

// ---------------- kernel 5: GEMM B  out[t] += w_row * (h @ W2 + b2) ----------------
// grid: routed 8*16*4=512 blocks, shared 16*4=64 -> 576. 256 threads.
__global__ __launch_bounds__(256) void gemmB_k(
    const u16* __restrict__ hbuf, const float* __restrict__ W2,
    const float* __restrict__ b2, const float* __restrict__ Ws2,
    const float* __restrict__ bs2, const int* __restrict__ cnt,
    const int* __restrict__ offs, const int* __restrict__ rtok,
    const float* __restrict__ wrow, float* __restrict__ out) {
    int vb = blockIdx.x;
    int tid = threadIdx.x;
    int rt, ct, Mloc;
    bool sh = vb >= 512;
    const float *Bsrc, *bias;
    int aRowBase;
    if (!sh) {
        int e = vb >> 6;
        rt = (vb >> 2) & 15; ct = vb & 3;
        int M = cnt[e];
        if (rt * 128 >= M) return;
        Mloc = M - rt * 128;
        aRowBase = offs[e] + rt * 128;
        Bsrc = W2 + (size_t)e * FF * DD;
        bias = b2 + e * DD;
    } else {
        int v = vb - 512;
        rt = v >> 2; ct = v & 3;
        Mloc = 128;
        aRowBase = 4096 + rt * 128;
        Bsrc = Ws2;
        bias = bs2;
    }
    int n0 = ct * 128;
    int lane = tid & 63, w = tid >> 6, ln = lane & 15, quad = lane >> 4;

    __shared__ __align__(16) u16 As[128 * 32];
    __shared__ __align__(16) u16 Bst[128 * 32];

    float4v acc[4][4];
#pragma unroll
    for (int a = 0; a < 4; ++a)
#pragma unroll
        for (int b = 0; b < 4; ++b) acc[a][b] = (float4v){0.f, 0.f, 0.f, 0.f};

    const u16* Asrc = hbuf + (size_t)aRowBase * FF;

    for (int kt = 0; kt < FF / 32; ++kt) {
        int k0 = kt * 32;
#pragma unroll
        for (int r = 0; r < 2; ++r) {
            int lr = (tid >> 2) + r * 64;
            int kg = tid & 3;
            ushort8v v = (ushort8v){0,0,0,0,0,0,0,0};
            if (lr < Mloc) v = *(const ushort8v*)(Asrc + (size_t)lr * FF + k0 + kg * 8);
            *(ushort8v*)&As[lr * 32 + kg * 8] = v;
        }
        {
            int k2 = tid & 15;
            int ng = tid >> 4;
            const float* bp = Bsrc + (size_t)(k0 + 2 * k2) * DD + n0 + ng * 8;
            float4v a0 = *(const float4v*)bp;
            float4v a1 = *(const float4v*)(bp + 4);
            float4v c0 = *(const float4v*)(bp + DD);
            float4v c1 = *(const float4v*)(bp + DD + 4);
#pragma unroll
            for (int j = 0; j < 4; ++j) {
                unsigned u = (unsigned)f2bf(a0[j]) | ((unsigned)f2bf(c0[j]) << 16);
                *(unsigned*)&Bst[(ng * 8 + j) * 32 + 2 * k2] = u;
            }
#pragma unroll
            for (int j = 0; j < 4; ++j) {
                unsigned u = (unsigned)f2bf(a1[j]) | ((unsigned)f2bf(c1[j]) << 16);
                *(unsigned*)&Bst[(ng * 8 + 4 + j) * 32 + 2 * k2] = u;
            }
        }
        __syncthreads();
        short8 Af[4], Bf[4];
#pragma unroll
        for (int a = 0; a < 4; ++a)
            Af[a] = *(const short8*)&As[((w & 1) * 64 + a * 16 + ln) * 32 + quad * 8];
#pragma unroll
        for (int b = 0; b < 4; ++b)
            Bf[b] = *(const short8*)&Bst[((w >> 1) * 64 + b * 16 + ln) * 32 + quad * 8];
#pragma unroll
        for (int a = 0; a < 4; ++a)
#pragma unroll
            for (int b = 0; b < 4; ++b)
                acc[a][b] = __builtin_amdgcn_mfma_f32_16x16x32_bf16(Af[a], Bf[b], acc[a][b], 0, 0, 0);
        __syncthreads();
    }
    // epilogue: atomically accumulate w * (gemm + bias) into out[t]
    float bv[4];
#pragma unroll
    for (int b = 0; b < 4; ++b) bv[b] = bias[n0 + (w >> 1) * 64 + b * 16 + ln];
#pragma unroll
    for (int a = 0; a < 4; ++a) {
#pragma unroll
        for (int i = 0; i < 4; ++i) {
            int lr = (w & 1) * 64 + a * 16 + quad * 4 + i;
            if (lr < Mloc) {
                int row = aRowBase + lr;
                int t; float wr;
                if (sh) { t = row - 4096; wr = 0.5f; }
                else    { t = rtok[row];  wr = wrow[row]; }
                float* op = out + (size_t)t * DD;
#pragma unroll
                for (int b = 0; b < 4; ++b) {
                    int n = n0 + (w >> 1) * 64 + b * 16 + ln;
                    atomicAdd(op + n, wr * (acc[a][b][i] + bv[b]));
                }
            }
        }
    }
}

// ---------------- launcher ----------------
extern "C" void kernel_launch(void* const* d_in, const int* in_sizes, int n_in,
                              void* d_out, int out_size, void* d_ws, size_t ws_size,
                              hipStream_t stream) {
    const float* x   = (const float*)d_in[0];
    const float* Wg  = (const float*)d_in[1];
    const float* bg  = (const float*)d_in[2];
    const float* W1  = (const float*)d_in[3];
    const float* b1  = (const float*)d_in[4];
    const float* W2  = (const float*)d_in[5];
    const float* b2  = (const float*)d_in[6];
    const float* Ws1 = (const float*)d_in[7];
    const float* bs1 = (const float*)d_in[8];
    const float* Ws2 = (const float*)d_in[9];
    const float* bs2 = (const float*)d_in[10];
    float* out = (float*)d_out;

    char* ws = (char*)d_ws;
    u16*   hbuf = (u16*)(ws + WS_HB);
    u16*   xg   = (u16*)(ws + WS_XG);
    int*   cnt  = (int*)(ws + WS_CNT);
    int*   offs = (int*)(ws + WS_OFFS);
    int*   fill = (int*)(ws + WS_FILL);
    int*   metaE = (int*)(ws + WS_ME);
    float* metaW = (float*)(ws + WS_MW);
    int*   rtok  = (int*)(ws + WS_RT);
    float* wrow  = (float*)(ws + WS_WROW);

    // out is poisoned (0xAA) before every timed call -> zero it (accumulated into)
    hipMemsetAsync(d_out, 0, (size_t)out_size * sizeof(float), stream);
    // zero cnt + offs + fill (contiguous 96 B)
    hipMemsetAsync(ws + WS_CNT, 0, 96, stream);

    gate_k<<<TT, 64, 0, stream>>>(x, Wg, bg, cnt, metaE, metaW);
    scan_k<<<1, 64, 0, stream>>>(cnt, offs);
    fill_k<<<TT, 64, 0, stream>>>(x, offs, fill, metaE, metaW, rtok, wrow, xg);
    gemmA_k<<<2304, 256, 0, stream>>>(xg, W1, b1, Ws1, bs1, cnt, offs, hbuf);
    gemmB_k<<<576, 256, 0, stream>>>(hbuf, W2, b2, Ws2, bs2, cnt, offs, rtok, wrow, out);
}

// Round 3
// 318.139 us; speedup vs baseline: 1.3300x; 1.3300x over previous
//
#include <hip/hip_runtime.h>
#include <hip/hip_bf16.h>
#include <stdint.h>

// Problem constants (S=1024, B=2 -> T=2048 tokens)
#define TT 2048
#define DD 512
#define FF 2048
#define EE 8

typedef unsigned short u16;
typedef __attribute__((ext_vector_type(8))) unsigned short ushort8v;
typedef __attribute__((ext_vector_type(8))) short short8;     // bf16x8 frag (4 VGPRs)
typedef __attribute__((ext_vector_type(4))) float float4v;

__device__ __forceinline__ u16 f2bf(float f) {
    unsigned u = __float_as_uint(f);
    u += 0x7FFF + ((u >> 16) & 1);   // round-to-nearest-even
    return (u16)(u >> 16);
}

// async global->LDS, 16B per lane; LDS dest = wave-uniform base + lane*16
__device__ __forceinline__ void gl_lds16(const u16* g, u16* l) {
    __builtin_amdgcn_global_load_lds(
        (const __attribute__((address_space(1))) unsigned int*)g,
        (__attribute__((address_space(3))) unsigned int*)l, 16, 0, 0);
}

// ---------------- workspace layout (bytes) ----------------
// hbuf bf16 [6144][2048] : rows 0..4095 routed (bucket order), 4096+t shared
// xg   bf16 [6144][512]  : rows 0..4095 gathered x (bucket order), 4096+t = x[t]
// Wt   bf16 [9][1M]      : transposed weights; W1t [F][D] for gemmA, then
//                          overwritten with W2t [D][F] for gemmB (stream-serial)
#define WS_HB   0ull
#define WS_XG   (WS_HB + 6144ull*2048*2)            // 25,165,824
#define WS_WT   (WS_XG + 6144ull*512*2)             // 31,457,280
#define WS_CNT  (WS_WT + 9ull*2048*512*2)           // 50,331,648
#define WS_OFFS (WS_CNT + 32)
#define WS_FILL (WS_OFFS + 32)
#define WS_ME   (WS_FILL + 32)                      // int  [2048][2] expert ids
#define WS_MW   (WS_ME + 4096*4)                    // float[2048][2] weights
#define WS_RT   (WS_MW + 4096*4)                    // int  rtok[4096] row -> token
#define WS_WROW (WS_RT + 4096*4)                    // float wrow[4096] row -> weight
// total ~50.4 MB

// ---------------- conv: fp32 [R][C] -> bf16 [C][R], 9 matrices ----------------
// grid = 9*256 blocks of 256. tiles are 64x64. shC = log2(C/64).
__global__ __launch_bounds__(256) void conv_k(const float* __restrict__ srcE,
                                              const float* __restrict__ srcS,
                                              u16* __restrict__ dst,
                                              int R, int C, int shC) {
    int mid = blockIdx.x >> 8;
    int t2  = blockIdx.x & 255;
    int tr = t2 >> shC, tc = t2 & ((1 << shC) - 1);
    int r0 = tr * 64, c0 = tc * 64;
    const float* src = (mid < 8) ? srcE + (size_t)mid * R * C : srcS;
    u16* dstm = dst + (size_t)mid * R * C;
    int t = threadIdx.x;
    __shared__ __align__(16) u16 Ls[64 * 72];
#pragma unroll
    for (int i = 0; i < 4; ++i) {
        int rr = (t >> 4) + i * 16;
        int cc = (t & 15) * 4;
        float4v v = *(const float4v*)(src + (size_t)(r0 + rr) * C + c0 + cc);
#pragma unroll
        for (int j = 0; j < 4; ++j) Ls[(cc + j) * 72 + rr] = f2bf(v[j]);
    }
    __syncthreads();
#pragma unroll
    for (int jj = 0; jj < 2; ++jj) {
        int slot = t + jj * 256;
        int cc = slot >> 3;
        int r8 = (slot & 7) * 8;
        ushort8v o = *(const ushort8v*)&Ls[cc * 72 + r8];
        *(ushort8v*)(dstm + (size_t)(c0 + cc) * R + r0 + r8) = o;
    }
}

// ---------------- kernel 1: gate (fp32 math, matches np ref) ----------------
__global__ void gate_k(const float* __restrict__ x, const float* __restrict__ Wg,
                       const float* __restrict__ bg,
                       int* __restrict__ cnt, int* __restrict__ metaE,
                       float* __restrict__ metaW) {
    int t = blockIdx.x;
    int lane = threadIdx.x;   // 64
    const float* xp = x + (size_t)t * DD + lane * 8;
    float4v x0 = *(const float4v*)xp;
    float4v x1 = *(const float4v*)(xp + 4);
    float xf[8] = {x0[0], x0[1], x0[2], x0[3], x1[0], x1[1], x1[2], x1[3]};
    float acc[EE] = {0.f, 0.f, 0.f, 0.f, 0.f, 0.f, 0.f, 0.f};
#pragma unroll
    for (int g = 0; g < 8; ++g) {
        int d = lane * 8 + g;
        const float* wp = Wg + (size_t)d * EE;
        float4v w0 = *(const float4v*)wp;
        float4v w1 = *(const float4v*)(wp + 4);
        acc[0] += xf[g] * w0[0]; acc[1] += xf[g] * w0[1];
        acc[2] += xf[g] * w0[2]; acc[3] += xf[g] * w0[3];
        acc[4] += xf[g] * w1[0]; acc[5] += xf[g] * w1[1];
        acc[6] += xf[g] * w1[2]; acc[7] += xf[g] * w1[3];
    }
#pragma unroll
    for (int off = 1; off < 64; off <<= 1) {
#pragma unroll
        for (int e = 0; e < EE; ++e) acc[e] += __shfl_xor(acc[e], off, 64);
    }
    if (lane == 0) {
#pragma unroll
        for (int e = 0; e < EE; ++e) acc[e] += bg[e];
        int e0 = 0; float l0 = acc[0];
#pragma unroll
        for (int e = 1; e < EE; ++e) if (acc[e] > l0) { l0 = acc[e]; e0 = e; }
        int e1 = -1; float l1 = -3.4e38f;
#pragma unroll
        for (int e = 0; e < EE; ++e)
            if (e != e0 && acc[e] > l1) { l1 = acc[e]; e1 = e; }
        float ex = __expf(l1 - l0);      // l1 <= l0, stable
        float w0 = 1.f / (1.f + ex);
        float w1 = 1.f - w0;
        atomicAdd(&cnt[e0], 1);
        atomicAdd(&cnt[e1], 1);
        metaE[2 * t] = e0; metaE[2 * t + 1] = e1;
        metaW[2 * t] = w0; metaW[2 * t + 1] = w1;
    }
}

// ---------------- kernel 2: scan ----------------
__global__ void scan_k(const int* __restrict__ cnt, int* __restrict__ offs) {
    if (threadIdx.x == 0 && blockIdx.x == 0) {
        int s = 0;
        for (int e = 0; e < EE; ++e) { offs[e] = s; s += cnt[e]; }
    }
}

// ---------------- kernel 3: fill (assign rows + gather x -> bf16) ----------------
__global__ void fill_k(const float* __restrict__ x, const int* __restrict__ offs,
                       int* __restrict__ fill, const int* __restrict__ metaE,
                       const float* __restrict__ metaW, int* __restrict__ rtok,
                       float* __restrict__ wrow, u16* __restrict__ xg) {
    int t = blockIdx.x;
    int lane = threadIdx.x;
    int r0 = 0, r1 = 0;
    if (lane == 0) {
        int e0 = metaE[2 * t], e1 = metaE[2 * t + 1];
        r0 = offs[e0] + atomicAdd(&fill[e0], 1);
        r1 = offs[e1] + atomicAdd(&fill[e1], 1);
        rtok[r0] = t; rtok[r1] = t;
        wrow[r0] = metaW[2 * t];
        wrow[r1] = metaW[2 * t + 1];
    }
    r0 = __shfl(r0, 0, 64);
    r1 = __shfl(r1, 0, 64);
    const float* xp = x + (size_t)t * DD + lane * 8;
    float4v v0 = *(const float4v*)xp;
    float4v v1 = *(const float4v*)(xp + 4);
    ushort8v xv;
#pragma unroll
    for (int j = 0; j < 4; ++j) xv[j] = f2bf(v0[j]);
#pragma unroll
    for (int j = 0; j < 4; ++j) xv[4 + j] = f2bf(v1[j]);
    *(ushort8v*)(xg + (size_t)r0 * DD + lane * 8) = xv;
    *(ushort8v*)(xg + (size_t)r1 * DD + lane * 8) = xv;
    *(ushort8v*)(xg + (size_t)(4096 + t) * DD + lane * 8) = xv;  // shared-expert copy
}

// ---------------- kernel 4: GEMM A  h = relu(A @ W1 + b1) ----------------
// A: xg [row][k=D], B: W1t [n=F][k=D]. grid 2048 routed (e = vb&7 XCD swizzle)
// + 256 shared. 256 threads. m97-style global_load_lds staging.
__global__ __launch_bounds__(256) void gemmA_k(
    const u16* __restrict__ xg, const u16* __restrict__ Wt,
    const float* __restrict__ b1, const float* __restrict__ bs1,
    const int* __restrict__ cnt, const int* __restrict__ offs,
    u16* __restrict__ hbuf) {
    int vb = blockIdx.x;
    int tid = threadIdx.x;
    int rt, ct, Mloc, hRowBase;
    const u16 *Asrc, *Bsrc;
    const float* bias;
    if (vb < 2048) {
        int e = vb & 7;               // XCD-affine expert mapping
        int r2 = vb >> 3;             // 0..255
        rt = r2 >> 4; ct = r2 & 15;
        int M = cnt[e];
        if (rt * 128 >= M) return;
        Mloc = M - rt * 128;
        int rb = offs[e] + rt * 128;
        Asrc = xg + (size_t)rb * DD;
        Bsrc = Wt + (size_t)e * FF * DD;
        bias = b1 + e * FF;
        hRowBase = rb;
    } else {
        int v = vb - 2048;
        rt = v >> 4; ct = v & 15;
        Mloc = 128;
        Asrc = xg + (size_t)(4096 + rt * 128) * DD;
        Bsrc = Wt + (size_t)8 * FF * DD;
        bias = bs1;
        hRowBase = 4096 + rt * 128;
    }
    int n0 = ct * 128;
    int lane = tid & 63, w = tid >> 6, ln = lane & 15, quad = lane >> 4;
    int rowL = lane >> 2;            // 0..15 within 16-row segment
    int kcL = (lane & 3) * 8;        // k element offset of this lane's 16B

    __shared__ __align__(16) u16 As[128 * 32];
    __shared__ __align__(16) u16 Bs[128 * 32];

    float4v acc[4][4];
#pragma unroll
    for (int a = 0; a < 4; ++a)
#pragma unroll
        for (int b = 0; b < 4; ++b) acc[a][b] = (float4v){0.f, 0.f, 0.f, 0.f};

    for (int kt = 0; kt < DD / 32; ++kt) {
        int k0 = kt * 32;
#pragma unroll
        for (int i = 0; i < 2; ++i) {
            int seg = w * 2 + i;
            int row = seg * 16 + rowL;
            // A rows beyond Mloc read neighboring bucket rows: finite garbage,
            // masked at epilogue (MFMA row m only affects C row m).
            gl_lds16(Asrc + (size_t)row * DD + k0 + kcL, &As[seg * 512]);
            gl_lds16(Bsrc + (size_t)(n0 + row) * DD + k0 + kcL, &Bs[seg * 512]);
        }
        __syncthreads();
        short8 Af[4], Bf[4];
#pragma unroll
        for (int a = 0; a < 4; ++a)
            Af[a] = *(const short8*)&As[((w & 1) * 64 + a * 16 + ln) * 32 + quad * 8];
#pragma unroll
        for (int b = 0; b < 4; ++b)
            Bf[b] = *(const short8*)&Bs[((w >> 1) * 64 + b * 16 + ln) * 32 + quad * 8];
#pragma unroll
        for (int a = 0; a < 4; ++a)
#pragma unroll
            for (int b = 0; b < 4; ++b)
                acc[a][b] = __builtin_amdgcn_mfma_f32_16x16x32_bf16(Af[a], Bf[b], acc[a][b], 0, 0, 0);
        __syncthreads();
    }
    // epilogue: +b1, relu, store bf16
#pragma unroll
    for (int b = 0; b < 4; ++b) {
        int n = n0 + (w >> 1) * 64 + b * 16 + ln;
        float bv = bias[n];
#pragma unroll
        for (int a = 0; a < 4; ++a) {
#pragma unroll
            for (int i = 0; i < 4; ++i) {
                int lr = (w & 1) * 64 + a * 16 + quad * 4 + i;
                if (lr < Mloc) {
                    float v = acc[a][b][i] + bv;
                    v = v > 0.f ? v : 0.f;
                    hbuf[(size_t)(hRowBase + lr) * FF + n] = f2bf(v);
                }
            }
        }
    }
}

// ---------------- kernel 5: GEMM B  out[t] += w_row * (h @ W2 + b2) ----------------
// A: hbuf [row][k=F], B: W2t [n=D][k=F]. K split x2 (ks in {0,1}, 1024 each).
// grid 1024 routed (e = vb&7) + 128 shared. bias only in ks==0 chunk.
__global__ __launch_bounds__(256) void gemmB_k(
    const u16* __restrict__ hbuf, const u16* __restrict__ Wt,
    const float* __restrict__ b2, const float* __restrict__ bs2,
    const int* __restrict__ cnt, const int* __restrict__ offs,
    const int* __restrict__ rtok, const float* __restrict__ wrow,
    float* __restrict__ out) {
    int vb = blockIdx.x;
    int tid = threadIdx.x;
    int rt, ct, ks, Mloc, aRowBase;
    bool sh = vb >= 1024;
    const u16* Bsrc;
    const float* bias;
    if (!sh) {
        int e = vb & 7;
        int r2 = vb >> 3;             // 0..127
        rt = r2 >> 3; ct = (r2 >> 1) & 3; ks = r2 & 1;
        int M = cnt[e];
        if (rt * 128 >= M) return;
        Mloc = M - rt * 128;
        aRowBase = offs[e] + rt * 128;
        Bsrc = Wt + (size_t)e * DD * FF;
        bias = b2 + e * DD;
    } else {
        int v = vb - 1024;
        rt = v >> 3; ct = (v >> 1) & 3; ks = v & 1;
        Mloc = 128;
        aRowBase = 4096 + rt * 128;
        Bsrc = Wt + (size_t)8 * DD * FF;
        bias = bs2;
    }
    int n0 = ct * 128;
    int lane = tid & 63, w = tid >> 6, ln = lane & 15, quad = lane >> 4;
    int rowL = lane >> 2;
    int kcL = (lane & 3) * 8;

    __shared__ __align__(16) u16 As[128 * 32];
    __shared__ __align__(16) u16 Bs[128 * 32];

    float4v acc[4][4];
#pragma unroll
    for (int a = 0; a < 4; ++a)
#pragma unroll
        for (int b = 0; b < 4; ++b) acc[a][b] = (float4v){0.f, 0.f, 0.f, 0.f};

    const u16* Asrc = hbuf + (size_t)aRowBase * FF;

    for (int kt = 0; kt < 32; ++kt) {
        int k0 = ks * 1024 + kt * 32;
#pragma unroll
        for (int i = 0; i < 2; ++i) {
            int seg = w * 2 + i;
            int row = seg * 16 + rowL;
            gl_lds16(Asrc + (size_t)row * FF + k0 + kcL, &As[seg * 512]);
            gl_lds16(Bsrc + (size_t)(n0 + row) * FF + k0 + kcL, &Bs[seg * 512]);
        }
        __syncthreads();
        short8 Af[4], Bf[4];
#pragma unroll
        for (int a = 0; a < 4; ++a)
            Af[a] = *(const short8*)&As[((w & 1) * 64 + a * 16 + ln) * 32 + quad * 8];
#pragma unroll
        for (int b = 0; b < 4; ++b)
            Bf[b] = *(const short8*)&Bs[((w >> 1) * 64 + b * 16 + ln) * 32 + quad * 8];
#pragma unroll
        for (int a = 0; a < 4; ++a)
#pragma unroll
            for (int b = 0; b < 4; ++b)
                acc[a][b] = __builtin_amdgcn_mfma_f32_16x16x32_bf16(Af[a], Bf[b], acc[a][b], 0, 0, 0);
        __syncthreads();
    }
    // epilogue: atomically accumulate w * (gemm + bias[ks==0 only]) into out[t]
    float bv[4];
#pragma unroll
    for (int b = 0; b < 4; ++b)
        bv[b] = (ks == 0) ? bias[n0 + (w >> 1) * 64 + b * 16 + ln] : 0.f;
#pragma unroll
    for (int a = 0; a < 4; ++a) {
#pragma unroll
        for (int i = 0; i < 4; ++i) {
            int lr = (w & 1) * 64 + a * 16 + quad * 4 + i;
            if (lr < Mloc) {
                int row = aRowBase + lr;
                int t; float wr;
                if (sh) { t = row - 4096; wr = 0.5f; }
                else    { t = rtok[row];  wr = wrow[row]; }
                float* op = out + (size_t)t * DD;
#pragma unroll
                for (int b = 0; b < 4; ++b) {
                    int n = n0 + (w >> 1) * 64 + b * 16 + ln;
                    atomicAdd(op + n, wr * (acc[a][b][i] + bv[b]));
                }
            }
        }
    }
}

// ---------------- launcher ----------------
extern "C" void kernel_launch(void* const* d_in, const int* in_sizes, int n_in,
                              void* d_out, int out_size, void* d_ws, size_t ws_size,
                              hipStream_t stream) {
    const float* x   = (const float*)d_in[0];
    const float* Wg  = (const float*)d_in[1];
    const float* bg  = (const float*)d_in[2];
    const float* W1  = (const float*)d_in[3];
    const float* b1  = (const float*)d_in[4];
    const float* W2  = (const float*)d_in[5];
    const float* b2  = (const float*)d_in[6];
    const float* Ws1 = (const float*)d_in[7];
    const float* bs1 = (const float*)d_in[8];
    const float* Ws2 = (const float*)d_in[9];
    const float* bs2 = (const float*)d_in[10];
    float* out = (float*)d_out;

    char* ws = (char*)d_ws;
    u16*   hbuf = (u16*)(ws + WS_HB);
    u16*   xg   = (u16*)(ws + WS_XG);
    u16*   Wt   = (u16*)(ws + WS_WT);
    int*   cnt  = (int*)(ws + WS_CNT);
    int*   offs = (int*)(ws + WS_OFFS);
    int*   fill = (int*)(ws + WS_FILL);
    int*   metaE = (int*)(ws + WS_ME);
    float* metaW = (float*)(ws + WS_MW);
    int*   rtok  = (int*)(ws + WS_RT);
    float* wrow  = (float*)(ws + WS_WROW);

    // out is poisoned (0xAA) before every timed call -> zero it (accumulated into)
    hipMemsetAsync(d_out, 0, (size_t)out_size * sizeof(float), stream);
    // zero cnt + offs + fill (contiguous 96 B)
    hipMemsetAsync(ws + WS_CNT, 0, 96, stream);

    // W1 / Ws1 -> Wt as [F][D] bf16
    conv_k<<<2304, 256, 0, stream>>>(W1, Ws1, Wt, DD, FF, 5);
    gate_k<<<TT, 64, 0, stream>>>(x, Wg, bg, cnt, metaE, metaW);
    scan_k<<<1, 64, 0, stream>>>(cnt, offs);
    fill_k<<<TT, 64, 0, stream>>>(x, offs, fill, metaE, metaW, rtok, wrow, xg);
    gemmA_k<<<2304, 256, 0, stream>>>(xg, Wt, b1, bs1, cnt, offs, hbuf);
    // W2 / Ws2 -> Wt as [D][F] bf16 (overwrites W1t; gemmA already done)
    conv_k<<<2304, 256, 0, stream>>>(W2, Ws2, Wt, FF, DD, 3);
    gemmB_k<<<1152, 256, 0, stream>>>(hbuf, Wt, b2, bs2, cnt, offs, rtok, wrow, out);
}

// Round 4
// 228.907 us; speedup vs baseline: 1.8484x; 1.3898x over previous
//
#include <hip/hip_runtime.h>
#include <hip/hip_bf16.h>
#include <stdint.h>

// Problem constants (S=1024, B=2 -> T=2048 tokens)
#define TT 2048
#define DD 512
#define FF 2048
#define EE 8

typedef unsigned short u16;
typedef __attribute__((ext_vector_type(8))) unsigned short ushort8v;
typedef __attribute__((ext_vector_type(8))) short short8;     // bf16x8 frag (4 VGPRs)
typedef __attribute__((ext_vector_type(4))) float float4v;

__device__ __forceinline__ u16 f2bf(float f) {
    unsigned u = __float_as_uint(f);
    u += 0x7FFF + ((u >> 16) & 1);   // round-to-nearest-even
    return (u16)(u >> 16);
}

// async global->LDS, 16B per lane; LDS dest = wave-uniform base + lane*16.
// Global address may be per-lane divergent (gather) - only LDS side is linear.
__device__ __forceinline__ void gl_lds16(const u16* g, u16* l) {
    __builtin_amdgcn_global_load_lds(
        (const __attribute__((address_space(1))) unsigned int*)g,
        (__attribute__((address_space(3))) unsigned int*)l, 16, 0, 0);
}

// ---------------- workspace layout (bytes) ----------------
// hbuf bf16 [6144][2048] : rows 0..4095 routed (bucket order), 4096+t shared
// xg   bf16 [2048][512]  : x rows converted to bf16 (token order)
// Wt   bf16 [9][1M]      : transposed weights; W1t [F][D] for gemmA, then
//                          overwritten with W2t [D][F] for gemmB (stream-serial)
#define WS_HB   0ull
#define WS_XG   (WS_HB + 6144ull*2048*2)            // 25,165,824
#define WS_WT   (WS_XG + 2048ull*512*2)             // 27,262,976
#define WS_RTG  (WS_WT + 9ull*2048*512*2)           // 46,137,344 : routing int[16] = offs[8],cnt[8]
#define WS_ME   (WS_RTG + 64)                       // int  [2048][2] expert ids
#define WS_MW   (WS_ME + 4096*4)                    // float[2048][2] weights
#define WS_RT   (WS_MW + 4096*4)                    // int  rtok[4096] bucket row -> token
#define WS_WROW (WS_RT + 4096*4)                    // float wrow[4096] bucket row -> weight
// total ~46.2 MB

// ---------------- conv: fp32 [R][C] -> bf16 [C][R], 9 matrices ----------------
// grid = 9*256 blocks of 256. tiles are 64x64. shC = log2(C/64).
__global__ __launch_bounds__(256) void conv_k(const float* __restrict__ srcE,
                                              const float* __restrict__ srcS,
                                              u16* __restrict__ dst,
                                              int R, int C, int shC) {
    int mid = blockIdx.x >> 8;
    int t2  = blockIdx.x & 255;
    int tr = t2 >> shC, tc = t2 & ((1 << shC) - 1);
    int r0 = tr * 64, c0 = tc * 64;
    const float* src = (mid < 8) ? srcE + (size_t)mid * R * C : srcS;
    u16* dstm = dst + (size_t)mid * R * C;
    int t = threadIdx.x;
    __shared__ __align__(16) u16 Ls[64 * 72];
#pragma unroll
    for (int i = 0; i < 4; ++i) {
        int rr = (t >> 4) + i * 16;
        int cc = (t & 15) * 4;
        float4v v = *(const float4v*)(src + (size_t)(r0 + rr) * C + c0 + cc);
#pragma unroll
        for (int j = 0; j < 4; ++j) Ls[(cc + j) * 72 + rr] = f2bf(v[j]);
    }
    __syncthreads();
#pragma unroll
    for (int jj = 0; jj < 2; ++jj) {
        int slot = t + jj * 256;
        int cc = slot >> 3;
        int r8 = (slot & 7) * 8;
        ushort8v o = *(const ushort8v*)&Ls[cc * 72 + r8];
        *(ushort8v*)(dstm + (size_t)(c0 + cc) * R + r0 + r8) = o;
    }
}

// ---------------- gate: logits (fp32, matches np ref) + top2 + x->bf16 ----------------
// NO device atomics (round-3 postmortem: 4096 same-line atomics cost ~50us).
__global__ void gate_k(const float* __restrict__ x, const float* __restrict__ Wg,
                       const float* __restrict__ bg,
                       int* __restrict__ metaE, float* __restrict__ metaW,
                       u16* __restrict__ xg) {
    int t = blockIdx.x;
    int lane = threadIdx.x;   // 64
    const float* xp = x + (size_t)t * DD + lane * 8;
    float4v x0 = *(const float4v*)xp;
    float4v x1 = *(const float4v*)(xp + 4);
    float xf[8] = {x0[0], x0[1], x0[2], x0[3], x1[0], x1[1], x1[2], x1[3]};
    float acc[EE] = {0.f, 0.f, 0.f, 0.f, 0.f, 0.f, 0.f, 0.f};
#pragma unroll
    for (int g = 0; g < 8; ++g) {
        int d = lane * 8 + g;
        const float* wp = Wg + (size_t)d * EE;
        float4v w0 = *(const float4v*)wp;
        float4v w1 = *(const float4v*)(wp + 4);
        acc[0] += xf[g] * w0[0]; acc[1] += xf[g] * w0[1];
        acc[2] += xf[g] * w0[2]; acc[3] += xf[g] * w0[3];
        acc[4] += xf[g] * w1[0]; acc[5] += xf[g] * w1[1];
        acc[6] += xf[g] * w1[2]; acc[7] += xf[g] * w1[3];
    }
#pragma unroll
    for (int off = 1; off < 64; off <<= 1) {
#pragma unroll
        for (int e = 0; e < EE; ++e) acc[e] += __shfl_xor(acc[e], off, 64);
    }
    // bf16 copy of x (reuses loaded row)
    ushort8v xv;
#pragma unroll
    for (int j = 0; j < 4; ++j) xv[j] = f2bf(x0[j]);
#pragma unroll
    for (int j = 0; j < 4; ++j) xv[4 + j] = f2bf(x1[j]);
    *(ushort8v*)(xg + (size_t)t * DD + lane * 8) = xv;
    if (lane == 0) {
#pragma unroll
        for (int e = 0; e < EE; ++e) acc[e] += bg[e];
        int e0 = 0; float l0 = acc[0];
#pragma unroll
        for (int e = 1; e < EE; ++e) if (acc[e] > l0) { l0 = acc[e]; e0 = e; }
        int e1 = -1; float l1 = -3.4e38f;
#pragma unroll
        for (int e = 0; e < EE; ++e)
            if (e != e0 && acc[e] > l1) { l1 = acc[e]; e1 = e; }
        float ex = __expf(l1 - l0);      // l1 <= l0, stable
        float w0 = 1.f / (1.f + ex);
        float w1 = 1.f - w0;
        metaE[2 * t] = e0; metaE[2 * t + 1] = e1;
        metaW[2 * t] = w0; metaW[2 * t + 1] = w1;
    }
}

// ---------------- rank: ballot-based bucket assignment, 1 block, 0 atomics ----------------
// 1024 threads = 16 waves; 4096 entries in 64 segments of 64.
__global__ __launch_bounds__(1024) void rank_k(const int* __restrict__ metaE,
                                               const float* __restrict__ metaW,
                                               int* __restrict__ routing,
                                               int* __restrict__ rtok,
                                               float* __restrict__ wrow) {
    int tid = threadIdx.x;
    int wv = tid >> 6, lane = tid & 63;
    __shared__ int segCnt[64][8];
    __shared__ int segBase[64][8];
    __shared__ int expOff[8];
    int myE[4], myRk[4];
    unsigned long long below = (lane == 0) ? 0ull : ((~0ull) >> (64 - lane));
#pragma unroll
    for (int r = 0; r < 4; ++r) {
        int entry = wv * 256 + r * 64 + lane;
        int e = metaE[entry];
        myE[r] = e;
        int rk = 0;
#pragma unroll
        for (int ee = 0; ee < 8; ++ee) {
            unsigned long long m = __ballot(e == ee);
            if (e == ee) rk = __popcll(m & below);
            if (lane == ee) segCnt[wv * 4 + r][ee] = __popcll(m);
        }
        myRk[r] = rk;
    }
    __syncthreads();
    if (tid < 8) {               // prefix over 64 segments, one thread per expert
        int s = 0;
        for (int g = 0; g < 64; ++g) { segBase[g][tid] = s; s += segCnt[g][tid]; }
        expOff[tid] = s;         // per-expert total (scanned below)
    }
    __syncthreads();
    if (tid == 0) {
        int s = 0;
        for (int e = 0; e < 8; ++e) { int c = expOff[e]; expOff[e] = s; s += c; }
    }
    __syncthreads();
    if (tid < 8) {
        routing[tid] = expOff[tid];                               // offs
        routing[8 + tid] = segBase[63][tid] + segCnt[63][tid];    // cnt
    }
#pragma unroll
    for (int r = 0; r < 4; ++r) {
        int entry = wv * 256 + r * 64 + lane;
        int e = myE[r];
        int row = expOff[e] + segBase[wv * 4 + r][e] + myRk[r];
        rtok[row] = entry >> 1;
        wrow[row] = metaW[entry];
    }
}

// ---------------- GEMM A  h = relu(A @ W1 + b1) ----------------
// A: xg[token][k=D] gathered per-lane via rtok; B: W1t [n=F][k=D].
// grid 2048 routed (e = vb&7 XCD swizzle) + 256 shared. 256 threads.
__global__ __launch_bounds__(256) void gemmA_k(
    const u16* __restrict__ xg, const u16* __restrict__ Wt,
    const float* __restrict__ b1, const float* __restrict__ bs1,
    const int* __restrict__ routing, const int* __restrict__ rtok,
    u16* __restrict__ hbuf) {
    const int* offs = routing;
    const int* cnt = routing + 8;
    int vb = blockIdx.x;
    int tid = threadIdx.x;
    int rt, ct, Mloc, hRowBase, rowBase;
    bool routed;
    const u16* Bsrc;
    const float* bias;
    if (vb < 2048) {
        int e = vb & 7;               // XCD-affine expert mapping
        int r2 = vb >> 3;             // 0..255
        rt = r2 >> 4; ct = r2 & 15;
        int M = cnt[e];
        if (rt * 128 >= M) return;
        Mloc = M - rt * 128;
        rowBase = offs[e] + rt * 128;  // bucket row base
        Bsrc = Wt + (size_t)e * FF * DD;
        bias = b1 + e * FF;
        hRowBase = rowBase;
        routed = true;
    } else {
        int v = vb - 2048;
        rt = v >> 4; ct = v & 15;
        Mloc = 128;
        rowBase = rt * 128;            // token base
        Bsrc = Wt + (size_t)8 * FF * DD;
        bias = bs1;
        hRowBase = 4096 + rt * 128;
        routed = false;
    }
    int n0 = ct * 128;
    int lane = tid & 63, w = tid >> 6, ln = lane & 15, quad = lane >> 4;
    int rowL = lane >> 2;            // 0..15 within 16-row segment
    int kcL = (lane & 3) * 8;        // k element offset of this lane's 16B

    // per-lane A gather bases (constant over K-loop)
    const u16* Abase[2];
#pragma unroll
    for (int i = 0; i < 2; ++i) {
        int seg = w * 2 + i;
        int rr = seg * 16 + rowL;
        int tok;
        if (routed) {
            int br = rowBase + rr;
            if (br > 4095) br = 4095;  // OOB: finite garbage, epilogue-masked
            tok = rtok[br];
        } else {
            tok = rowBase + rr;
        }
        Abase[i] = xg + (size_t)tok * DD + kcL;
    }

    __shared__ __align__(16) u16 As[128 * 32];
    __shared__ __align__(16) u16 Bs[128 * 32];

    float4v acc[4][4];
#pragma unroll
    for (int a = 0; a < 4; ++a)
#pragma unroll
        for (int b = 0; b < 4; ++b) acc[a][b] = (float4v){0.f, 0.f, 0.f, 0.f};

    for (int kt = 0; kt < DD / 32; ++kt) {
        int k0 = kt * 32;
#pragma unroll
        for (int i = 0; i < 2; ++i) {
            int seg = w * 2 + i;
            int row = seg * 16 + rowL;
            gl_lds16(Abase[i] + k0, &As[seg * 512]);
            gl_lds16(Bsrc + (size_t)(n0 + row) * DD + k0 + kcL, &Bs[seg * 512]);
        }
        __syncthreads();
        short8 Af[4], Bf[4];
#pragma unroll
        for (int a = 0; a < 4; ++a)
            Af[a] = *(const short8*)&As[((w & 1) * 64 + a * 16 + ln) * 32 + quad * 8];
#pragma unroll
        for (int b = 0; b < 4; ++b)
            Bf[b] = *(const short8*)&Bs[((w >> 1) * 64 + b * 16 + ln) * 32 + quad * 8];
#pragma unroll
        for (int a = 0; a < 4; ++a)
#pragma unroll
            for (int b = 0; b < 4; ++b)
                acc[a][b] = __builtin_amdgcn_mfma_f32_16x16x32_bf16(Af[a], Bf[b], acc[a][b], 0, 0, 0);
        __syncthreads();
    }
    // epilogue: +b1, relu, store bf16
#pragma unroll
    for (int b = 0; b < 4; ++b) {
        int n = n0 + (w >> 1) * 64 + b * 16 + ln;
        float bv = bias[n];
#pragma unroll
        for (int a = 0; a < 4; ++a) {
#pragma unroll
            for (int i = 0; i < 4; ++i) {
                int lr = (w & 1) * 64 + a * 16 + quad * 4 + i;
                if (lr < Mloc) {
                    float v = acc[a][b][i] + bv;
                    v = v > 0.f ? v : 0.f;
                    hbuf[(size_t)(hRowBase + lr) * FF + n] = f2bf(v);
                }
            }
        }
    }
}

// ---------------- GEMM B  out[t] += w_row * (h @ W2 + b2) ----------------
// A: hbuf [row][k=F], B: W2t [n=D][k=F]. K split x2 (ks in {0,1}, 1024 each).
// grid 1024 routed (e = vb&7) + 128 shared. bias only in ks==0 chunk.
__global__ __launch_bounds__(256) void gemmB_k(
    const u16* __restrict__ hbuf, const u16* __restrict__ Wt,
    const float* __restrict__ b2, const float* __restrict__ bs2,
    const int* __restrict__ routing, const int* __restrict__ rtok,
    const float* __restrict__ wrow, float* __restrict__ out) {
    const int* offs = routing;
    const int* cnt = routing + 8;
    int vb = blockIdx.x;
    int tid = threadIdx.x;
    int rt, ct, ks, Mloc, aRowBase;
    bool sh = vb >= 1024;
    const u16* Bsrc;
    const float* bias;
    if (!sh) {
        int e = vb & 7;
        int r2 = vb >> 3;             // 0..127
        rt = r2 >> 3; ct = (r2 >> 1) & 3; ks = r2 & 1;
        int M = cnt[e];
        if (rt * 128 >= M) return;
        Mloc = M - rt * 128;
        aRowBase = offs[e] + rt * 128;
        Bsrc = Wt + (size_t)e * DD * FF;
        bias = b2 + e * DD;
    } else {
        int v = vb - 1024;
        rt = v >> 3; ct = (v >> 1) & 3; ks = v & 1;
        Mloc = 128;
        aRowBase = 4096 + rt * 128;
        Bsrc = Wt + (size_t)8 * DD * FF;
        bias = bs2;
    }
    int n0 = ct * 128;
    int lane = tid & 63, w = tid >> 6, ln = lane & 15, quad = lane >> 4;
    int rowL = lane >> 2;
    int kcL = (lane & 3) * 8;

    __shared__ __align__(16) u16 As[128 * 32];
    __shared__ __align__(16) u16 Bs[128 * 32];

    float4v acc[4][4];
#pragma unroll
    for (int a = 0; a < 4; ++a)
#pragma unroll
        for (int b = 0; b < 4; ++b) acc[a][b] = (float4v){0.f, 0.f, 0.f, 0.f};

    const u16* Asrc = hbuf + (size_t)aRowBase * FF;

    for (int kt = 0; kt < 32; ++kt) {
        int k0 = ks * 1024 + kt * 32;
#pragma unroll
        for (int i = 0; i < 2; ++i) {
            int seg = w * 2 + i;
            int row = seg * 16 + rowL;
            gl_lds16(Asrc + (size_t)row * FF + k0 + kcL, &As[seg * 512]);
            gl_lds16(Bsrc + (size_t)(n0 + row) * FF + k0 + kcL, &Bs[seg * 512]);
        }
        __syncthreads();
        short8 Af[4], Bf[4];
#pragma unroll
        for (int a = 0; a < 4; ++a)
            Af[a] = *(const short8*)&As[((w & 1) * 64 + a * 16 + ln) * 32 + quad * 8];
#pragma unroll
        for (int b = 0; b < 4; ++b)
            Bf[b] = *(const short8*)&Bs[((w >> 1) * 64 + b * 16 + ln) * 32 + quad * 8];
#pragma unroll
        for (int a = 0; a < 4; ++a)
#pragma unroll
            for (int b = 0; b < 4; ++b)
                acc[a][b] = __builtin_amdgcn_mfma_f32_16x16x32_bf16(Af[a], Bf[b], acc[a][b], 0, 0, 0);
        __syncthreads();
    }
    // epilogue: atomically accumulate w * (gemm + bias[ks==0 only]) into out[t]
    // (3.1M atomics spread over 1M distinct addresses -> low contention)
    float bv[4];
#pragma unroll
    for (int b = 0; b < 4; ++b)
        bv[b] = (ks == 0) ? bias[n0 + (w >> 1) * 64 + b * 16 + ln] : 0.f;
#pragma unroll
    for (int a = 0; a < 4; ++a) {
#pragma unroll
        for (int i = 0; i < 4; ++i) {
            int lr = (w & 1) * 64 + a * 16 + quad * 4 + i;
            if (lr < Mloc) {
                int row = aRowBase + lr;
                int t; float wr;
                if (sh) { t = row - 4096; wr = 0.5f; }
                else    { t = rtok[row];  wr = wrow[row]; }
                float* op = out + (size_t)t * DD;
#pragma unroll
                for (int b = 0; b < 4; ++b) {
                    int n = n0 + (w >> 1) * 64 + b * 16 + ln;
                    atomicAdd(op + n, wr * (acc[a][b][i] + bv[b]));
                }
            }
        }
    }
}

// ---------------- launcher ----------------
extern "C" void kernel_launch(void* const* d_in, const int* in_sizes, int n_in,
                              void* d_out, int out_size, void* d_ws, size_t ws_size,
                              hipStream_t stream) {
    const float* x   = (const float*)d_in[0];
    const float* Wg  = (const float*)d_in[1];
    const float* bg  = (const float*)d_in[2];
    const float* W1  = (const float*)d_in[3];
    const float* b1  = (const float*)d_in[4];
    const float* W2  = (const float*)d_in[5];
    const float* b2  = (const float*)d_in[6];
    const float* Ws1 = (const float*)d_in[7];
    const float* bs1 = (const float*)d_in[8];
    const float* Ws2 = (const float*)d_in[9];
    const float* bs2 = (const float*)d_in[10];
    float* out = (float*)d_out;

    char* ws = (char*)d_ws;
    u16*   hbuf    = (u16*)(ws + WS_HB);
    u16*   xg      = (u16*)(ws + WS_XG);
    u16*   Wt      = (u16*)(ws + WS_WT);
    int*   routing = (int*)(ws + WS_RTG);
    int*   metaE   = (int*)(ws + WS_ME);
    float* metaW   = (float*)(ws + WS_MW);
    int*   rtok    = (int*)(ws + WS_RT);
    float* wrow    = (float*)(ws + WS_WROW);

    // out is poisoned (0xAA) before every timed call -> zero it (accumulated into)
    hipMemsetAsync(d_out, 0, (size_t)out_size * sizeof(float), stream);

    // W1 / Ws1 -> Wt as [F][D] bf16
    conv_k<<<2304, 256, 0, stream>>>(W1, Ws1, Wt, DD, FF, 5);
    gate_k<<<TT, 64, 0, stream>>>(x, Wg, bg, metaE, metaW, xg);
    rank_k<<<1, 1024, 0, stream>>>(metaE, metaW, routing, rtok, wrow);
    gemmA_k<<<2304, 256, 0, stream>>>(xg, Wt, b1, bs1, routing, rtok, hbuf);
    // W2 / Ws2 -> Wt as [D][F] bf16 (overwrites W1t; gemmA already done)
    conv_k<<<2304, 256, 0, stream>>>(W2, Ws2, Wt, FF, DD, 3);
    gemmB_k<<<1152, 256, 0, stream>>>(hbuf, Wt, b2, bs2, routing, rtok, wrow, out);
}